// Round 1
// baseline (139.538 us; speedup 1.0000x reference)
//
#include <hip/hip_runtime.h>
#include <stdint.h>

#define NN 2048
#define TPB 256
#define EPT 8          // NN / TPB
#define KNB 16

static constexpr unsigned long long EXCL = ~0ull;

__global__ __launch_bounds__(TPB) void encoder_mask_kernel(
    const float* __restrict__ D,      // [B,N,N]
    const int*   __restrict__ TWC,    // [B,N,N]
    const int*   __restrict__ depot,  // [B,N]
    float*       __restrict__ out)    // [B,N,N]
{
    const int row = blockIdx.x;       // b*N + i
    const int b   = row >> 11;
    const int i   = row & (NN - 1);
    const int t   = threadIdx.x;
    const int j0  = t * EPT;

    float*       orow   = out + (size_t)row * NN;
    const int*   deprow = depot + b * NN;
    const int    depot_i = deprow[i];

    // Fast path: depot[b,i]==1 -> entire row is ones; skip all reads of D/TWC.
    if (depot_i != 0) {
        const float4 ones = make_float4(1.f, 1.f, 1.f, 1.f);
        float4* o4 = reinterpret_cast<float4*>(orow + j0);
        o4[0] = ones;
        o4[1] = ones;
        return;
    }

    const float* drow = D   + (size_t)row * NN;
    const int*   trow = TWC + (size_t)row * NN;

    // Vectorized loads: 8 dists + 8 twc per thread (contiguous chunk).
    const float4 d0 = reinterpret_cast<const float4*>(drow + j0)[0];
    const float4 d1 = reinterpret_cast<const float4*>(drow + j0)[1];
    const int4   c0 = reinterpret_cast<const int4*>(trow + j0)[0];
    const int4   c1 = reinterpret_cast<const int4*>(trow + j0)[1];

    const float dv[EPT] = {d0.x, d0.y, d0.z, d0.w, d1.x, d1.y, d1.z, d1.w};
    const int   cv[EPT] = {c0.x, c0.y, c0.z, c0.w, c1.x, c1.y, c1.z, c1.w};

    // Build sortable keys: (dist_bits << 11) | j ; excluded -> EXCL sentinel.
    // dist in [0,1) -> bits < 2^30 -> key < 2^41 < EXCL. Index bits make keys unique.
    unsigned long long key[EPT];
    #pragma unroll
    for (int k = 0; k < EPT; ++k) {
        const int j = j0 + k;
        const bool excl = (cv[k] == 0) | (j == i);
        key[k] = excl ? EXCL
                      : ((((unsigned long long)__float_as_uint(dv[k])) << 11) |
                         (unsigned long long)(unsigned)j);
    }

    unsigned long long lmin = key[0];
    #pragma unroll
    for (int k = 1; k < EPT; ++k) lmin = (key[k] < lmin) ? key[k] : lmin;

    __shared__ unsigned long long wpart[2][TPB / 64];  // double-buffered per-wave partials
    __shared__ unsigned long long selq[TPB];           // 2048-byte selected bytemap

    selq[t] = 0ull;
    __syncthreads();

    const int wave = t >> 6;
    const int lane = t & 63;

    #pragma unroll 1
    for (int it = 0; it < KNB; ++it) {
        // Intra-wave min reduce (64 lanes).
        unsigned long long w = lmin;
        #pragma unroll
        for (int off = 32; off >= 1; off >>= 1) {
            const unsigned long long o = __shfl_xor(w, off);
            w = (o < w) ? o : w;
        }
        const int p = it & 1;
        if (lane == 0) wpart[p][wave] = w;
        __syncthreads();

        // Cross-wave min (uniform in block).
        unsigned long long g = wpart[p][0];
        {
            const unsigned long long g1 = wpart[p][1];
            const unsigned long long g2 = wpart[p][2];
            const unsigned long long g3 = wpart[p][3];
            g = (g1 < g) ? g1 : g;
            g = (g2 < g) ? g2 : g;
            g = (g3 < g) ? g3 : g;
        }
        if (g == EXCL) break;  // fewer than K unblocked entries; rest can't matter

        const int jwin = (int)(g & 2047u);
        if (t == 0) reinterpret_cast<unsigned char*>(selq)[jwin] = 1;

        // Owner (unique: index bits in key) removes the winner, recomputes local min.
        if (lmin == g) {
            unsigned long long nm = EXCL;
            #pragma unroll
            for (int k = 0; k < EPT; ++k) {
                if (key[k] == g) key[k] = EXCL;
                nm = (key[k] < nm) ? key[k] : nm;
            }
            lmin = nm;
        }
        // One barrier per iteration; wpart is parity double-buffered so the next
        // write can't race this iteration's reads.
    }
    __syncthreads();  // make final sel-bytemap writes visible

    // Output: depot_i==0 here, so mask = depot_j | (j==i) | selected(j).
    const unsigned long long selbits = selq[t];  // bytes for j0..j0+7 (little-endian)
    const int4 p0 = reinterpret_cast<const int4*>(deprow + j0)[0];
    const int4 p1 = reinterpret_cast<const int4*>(deprow + j0)[1];
    const int dpv[EPT] = {p0.x, p0.y, p0.z, p0.w, p1.x, p1.y, p1.z, p1.w};

    float ov[EPT];
    #pragma unroll
    for (int k = 0; k < EPT; ++k) {
        const int j = j0 + k;
        const bool sel = ((selbits >> (8 * k)) & 0xffull) != 0ull;
        const bool one = (dpv[k] != 0) | (j == i) | sel;
        ov[k] = one ? 1.0f : 0.0f;
    }
    float4* o4 = reinterpret_cast<float4*>(orow + j0);
    o4[0] = make_float4(ov[0], ov[1], ov[2], ov[3]);
    o4[1] = make_float4(ov[4], ov[5], ov[6], ov[7]);
}

extern "C" void kernel_launch(void* const* d_in, const int* in_sizes, int n_in,
                              void* d_out, int out_size, void* d_ws, size_t ws_size,
                              hipStream_t stream) {
    const float* D     = (const float*)d_in[0];   // distance_matrix [B,N,N]
    // d_in[1] = max_dist [B,1,1] — provably irrelevant to the output (see analysis)
    const int*   TWC   = (const int*)d_in[2];     // time_window_compatibility [B,N,N]
    const int*   depot = (const int*)d_in[3];     // depot [B,N]
    // d_in[4] = num_neighbors_encoder == 16 (compile-time KNB)

    float* outp = (float*)d_out;
    const int rows = in_sizes[3];                 // B*N = 16384

    encoder_mask_kernel<<<rows, TPB, 0, stream>>>(D, TWC, depot, outp);
}

// Round 2
// 48.364 us; speedup vs baseline: 2.8852x; 2.8852x over previous
//
#include <hip/hip_runtime.h>
#include <stdint.h>

#define NN 2048
#define TPB 256
#define EPT 8          // NN / TPB
#define KNB 16
#define CAP 128        // candidate capacity (power of two, = 2 per lane in one wave)

static constexpr unsigned long long EXCL = ~0ull;
// Threshold 0.0625f: dist_bits < 0x3D800000 -> candidate. Key = (dist_bits<<11)|j.
static constexpr unsigned long long T0KEY = ((unsigned long long)0x3D800000u) << 11;

__global__ __launch_bounds__(TPB) void encoder_mask_kernel(
    const float* __restrict__ D,      // [B,N,N]
    const int*   __restrict__ TWC,    // [B,N,N]
    const int*   __restrict__ depot,  // [B,N]
    float*       __restrict__ out)    // [B,N,N]
{
    const int row = blockIdx.x;       // b*N + i
    const int b   = row >> 11;
    const int i   = row & (NN - 1);
    const int t   = threadIdx.x;
    const int j0  = t * EPT;

    float*       orow   = out + (size_t)row * NN;
    const int*   deprow = depot + b * NN;
    const int    depot_i = deprow[i];

    // Fast path: depot[b,i]==1 -> entire row is ones; skip all reads of D/TWC.
    if (depot_i != 0) {
        const float4 ones = make_float4(1.f, 1.f, 1.f, 1.f);
        float4* o4 = reinterpret_cast<float4*>(orow + j0);
        o4[0] = ones;
        o4[1] = ones;
        return;
    }

    const float* drow = D   + (size_t)row * NN;
    const int*   trow = TWC + (size_t)row * NN;

    const float4 d0 = reinterpret_cast<const float4*>(drow + j0)[0];
    const float4 d1 = reinterpret_cast<const float4*>(drow + j0)[1];
    const int4   c0 = reinterpret_cast<const int4*>(trow + j0)[0];
    const int4   c1 = reinterpret_cast<const int4*>(trow + j0)[1];

    const float dv[EPT] = {d0.x, d0.y, d0.z, d0.w, d1.x, d1.y, d1.z, d1.w};
    const int   cv[EPT] = {c0.x, c0.y, c0.z, c0.w, c1.x, c1.y, c1.z, c1.w};

    // Sortable keys: (dist_bits << 11) | j ; excluded -> EXCL. dist in [0,1) ->
    // bits < 2^30 -> key < 2^41. Index bits make keys unique (exact tie-break).
    unsigned long long key[EPT];
    #pragma unroll
    for (int k = 0; k < EPT; ++k) {
        const int j = j0 + k;
        const bool excl = (cv[k] == 0) | (j == i);
        key[k] = excl ? EXCL
                      : ((((unsigned long long)__float_as_uint(dv[k])) << 11) |
                         (unsigned long long)(unsigned)j);
    }

    __shared__ unsigned long long cand[CAP];
    __shared__ unsigned long long selq[TPB];   // 2048-byte selected bytemap
    __shared__ unsigned long long wpart[2][TPB / 64];
    __shared__ int cnt;

    selq[t] = 0ull;
    if (t < CAP) cand[t] = EXCL;
    if (t == 0) cnt = 0;
    __syncthreads();

    // Filter: compact all keys below threshold into cand[] (order irrelevant —
    // full keys are sorted later, so the result is deterministic).
    #pragma unroll
    for (int k = 0; k < EPT; ++k) {
        if (key[k] < T0KEY) {
            const int p = atomicAdd(&cnt, 1);
            if (p < CAP) cand[p] = key[k];
        }
    }
    __syncthreads();

    const int c = cnt;
    const int wave = t >> 6;
    const int lane = t & 63;

    if (c >= KNB && c <= CAP) {
        // Exactness: c >= 16 keys have dist < T0, so the global 16 smallest keys
        // all lie in cand[]. Wave 0 bitonic-sorts 128 u64 (2 regs/lane) and marks
        // the 16 smallest. No block barriers inside.
        if (wave == 0) {
            unsigned long long v0 = cand[lane];        // idx = lane
            unsigned long long v1 = cand[lane + 64];   // idx = 64 + lane
            #pragma unroll
            for (int kk = 2; kk <= CAP; kk <<= 1) {
                #pragma unroll
                for (int j = kk >> 1; j > 0; j >>= 1) {
                    if (j == 64) {
                        // exchange v0<->v1 (idx differs in bit 6); kk==128 -> ascending
                        const unsigned long long mn = (v1 < v0) ? v1 : v0;
                        const unsigned long long mx = (v1 < v0) ? v0 : v1;
                        v0 = mn; v1 = mx;
                    } else {
                        {
                            const unsigned long long o = __shfl_xor(v0, j);
                            const int idx = lane;
                            const bool asc = ((idx & kk) == 0);
                            const bool up  = ((lane & j) == 0);
                            const unsigned long long mn = (o < v0) ? o : v0;
                            const unsigned long long mx = (o < v0) ? v0 : o;
                            v0 = (up == asc) ? mn : mx;
                        }
                        {
                            const unsigned long long o = __shfl_xor(v1, j);
                            const int idx = 64 | lane;
                            const bool asc = ((idx & kk) == 0);
                            const bool up  = ((lane & j) == 0);
                            const unsigned long long mn = (o < v1) ? o : v1;
                            const unsigned long long mx = (o < v1) ? v1 : o;
                            v1 = (up == asc) ? mn : mx;
                        }
                    }
                }
            }
            if (lane < KNB) {
                reinterpret_cast<unsigned char*>(selq)[(int)(v0 & 2047u)] = 1;
            }
        }
    } else {
        // Exact fallback (astronomically rare on this distribution; required for
        // determinism/correctness): iterative global-min extraction, K rounds.
        unsigned long long lmin = key[0];
        #pragma unroll
        for (int k = 1; k < EPT; ++k) lmin = (key[k] < lmin) ? key[k] : lmin;

        #pragma unroll 1
        for (int it = 0; it < KNB; ++it) {
            unsigned long long w = lmin;
            #pragma unroll
            for (int off = 32; off >= 1; off >>= 1) {
                const unsigned long long o = __shfl_xor(w, off);
                w = (o < w) ? o : w;
            }
            const int p = it & 1;
            if (lane == 0) wpart[p][wave] = w;
            __syncthreads();
            unsigned long long g = wpart[p][0];
            {
                const unsigned long long g1 = wpart[p][1];
                const unsigned long long g2 = wpart[p][2];
                const unsigned long long g3 = wpart[p][3];
                g = (g1 < g) ? g1 : g;
                g = (g2 < g) ? g2 : g;
                g = (g3 < g) ? g3 : g;
            }
            if (g == EXCL) break;
            const int jwin = (int)(g & 2047u);
            if (t == 0) reinterpret_cast<unsigned char*>(selq)[jwin] = 1;
            if (lmin == g) {
                unsigned long long nm = EXCL;
                #pragma unroll
                for (int k = 0; k < EPT; ++k) {
                    if (key[k] == g) key[k] = EXCL;
                    nm = (key[k] < nm) ? key[k] : nm;
                }
                lmin = nm;
            }
        }
    }
    __syncthreads();  // sel-bytemap visible to all

    // Output: depot_i==0 here, so mask = depot_j | (j==i) | selected(j).
    const unsigned long long selbits = selq[t];
    const int4 p0 = reinterpret_cast<const int4*>(deprow + j0)[0];
    const int4 p1 = reinterpret_cast<const int4*>(deprow + j0)[1];
    const int dpv[EPT] = {p0.x, p0.y, p0.z, p0.w, p1.x, p1.y, p1.z, p1.w};

    float ov[EPT];
    #pragma unroll
    for (int k = 0; k < EPT; ++k) {
        const int j = j0 + k;
        const bool sel = ((selbits >> (8 * k)) & 0xffull) != 0ull;
        const bool one = (dpv[k] != 0) | (j == i) | sel;
        ov[k] = one ? 1.0f : 0.0f;
    }
    float4* o4 = reinterpret_cast<float4*>(orow + j0);
    o4[0] = make_float4(ov[0], ov[1], ov[2], ov[3]);
    o4[1] = make_float4(ov[4], ov[5], ov[6], ov[7]);
}

extern "C" void kernel_launch(void* const* d_in, const int* in_sizes, int n_in,
                              void* d_out, int out_size, void* d_ws, size_t ws_size,
                              hipStream_t stream) {
    const float* D     = (const float*)d_in[0];   // distance_matrix [B,N,N]
    // d_in[1] = max_dist — provably irrelevant (blocked entries never survive)
    const int*   TWC   = (const int*)d_in[2];     // time_window_compatibility [B,N,N]
    const int*   depot = (const int*)d_in[3];     // depot [B,N]
    // d_in[4] = num_neighbors_encoder == 16 (compile-time KNB)

    float* outp = (float*)d_out;
    const int rows = in_sizes[3];                 // B*N = 16384

    encoder_mask_kernel<<<rows, TPB, 0, stream>>>(D, TWC, depot, outp);
}

// Round 3
// 47.240 us; speedup vs baseline: 2.9538x; 1.0238x over previous
//
#include <hip/hip_runtime.h>
#include <stdint.h>

#define NN 2048
#define TPB 256
#define EPT 8          // NN / TPB
#define KNB 16
#define CAP 128        // candidate capacity (<= TPB so one thread per candidate)

static constexpr unsigned long long EXCL = ~0ull;
// Threshold 0.0625f: dist_bits < 0x3D800000 -> candidate. Key = (dist_bits<<11)|j.
// ~1024 unblocked entries/row, P(candidate)=1/16 -> count ~ Bin(1024,1/16):
// mean 64, P(<16) ~ 2e-12, P(>128) ~ 1e-12; both fall back to the exact path.
static constexpr unsigned long long T0KEY = ((unsigned long long)0x3D800000u) << 11;

__global__ __launch_bounds__(TPB) void encoder_mask_kernel(
    const float* __restrict__ D,      // [B,N,N]
    const int*   __restrict__ TWC,    // [B,N,N]
    const int*   __restrict__ depot,  // [B,N]
    float*       __restrict__ out)    // [B,N,N]
{
    const int row = blockIdx.x;       // b*N + i
    const int b   = row >> 11;
    const int i   = row & (NN - 1);
    const int t   = threadIdx.x;
    const int j0  = t * EPT;

    float*       orow   = out + (size_t)row * NN;
    const int*   deprow = depot + b * NN;
    const int    depot_i = deprow[i];

    // Fast path: depot[b,i]==1 -> entire row is ones; skip all reads of D/TWC.
    if (depot_i != 0) {
        const float4 ones = make_float4(1.f, 1.f, 1.f, 1.f);
        float4* o4 = reinterpret_cast<float4*>(orow + j0);
        o4[0] = ones;
        o4[1] = ones;
        return;
    }

    const float* drow = D   + (size_t)row * NN;
    const int*   trow = TWC + (size_t)row * NN;

    const float4 d0 = reinterpret_cast<const float4*>(drow + j0)[0];
    const float4 d1 = reinterpret_cast<const float4*>(drow + j0)[1];
    const int4   c0 = reinterpret_cast<const int4*>(trow + j0)[0];
    const int4   c1 = reinterpret_cast<const int4*>(trow + j0)[1];

    const float dv[EPT] = {d0.x, d0.y, d0.z, d0.w, d1.x, d1.y, d1.z, d1.w};
    const int   cv[EPT] = {c0.x, c0.y, c0.z, c0.w, c1.x, c1.y, c1.z, c1.w};

    // Sortable keys: (dist_bits << 11) | j ; excluded -> EXCL. dist in [0,1) ->
    // bits < 2^30 -> key < 2^41. Index bits make keys unique (exact tie-break,
    // matching lax.top_k's lowest-index-first on equal distances).
    unsigned long long key[EPT];
    #pragma unroll
    for (int k = 0; k < EPT; ++k) {
        const int j = j0 + k;
        const bool excl = (cv[k] == 0) | (j == i);
        key[k] = excl ? EXCL
                      : ((((unsigned long long)__float_as_uint(dv[k])) << 11) |
                         (unsigned long long)(unsigned)j);
    }

    __shared__ unsigned long long cand[CAP];
    __shared__ unsigned long long selq[TPB];   // 2048-byte selected bytemap
    __shared__ unsigned long long wpart[2][TPB / 64];
    __shared__ int cnt;

    selq[t] = 0ull;
    if (t == 0) cnt = 0;
    __syncthreads();

    // Filter: compact all keys below threshold into cand[] (order irrelevant —
    // ranks are computed over full unique keys, so the result is deterministic).
    #pragma unroll
    for (int k = 0; k < EPT; ++k) {
        if (key[k] < T0KEY) {
            const int p = atomicAdd(&cnt, 1);
            if (p < CAP) cand[p] = key[k];
        }
    }
    __syncthreads();

    const int c = cnt;

    if (c >= KNB && c <= CAP) {
        // Exactness: c >= 16 keys have dist < T0, so the global 16 smallest keys
        // all lie in cand[]. Rank selection: thread t owns cand[t]; inner loop
        // address is wave-uniform -> LDS broadcast reads, no dependency chain.
        if (t < c) {
            const unsigned long long mykey = cand[t];
            int rank = 0;
            #pragma unroll 4
            for (int q = 0; q < c; ++q) {
                rank += (cand[q] < mykey) ? 1 : 0;
            }
            if (rank < KNB) {
                reinterpret_cast<unsigned char*>(selq)[(int)(mykey & 2047u)] = 1;
            }
        }
    } else {
        // Exact fallback (astronomically rare; required for correctness):
        // iterative global-min extraction, K rounds.
        const int wave = t >> 6;
        const int lane = t & 63;
        unsigned long long lmin = key[0];
        #pragma unroll
        for (int k = 1; k < EPT; ++k) lmin = (key[k] < lmin) ? key[k] : lmin;

        #pragma unroll 1
        for (int it = 0; it < KNB; ++it) {
            unsigned long long w = lmin;
            #pragma unroll
            for (int off = 32; off >= 1; off >>= 1) {
                const unsigned long long o = __shfl_xor(w, off);
                w = (o < w) ? o : w;
            }
            const int p = it & 1;
            if (lane == 0) wpart[p][wave] = w;
            __syncthreads();
            unsigned long long g = wpart[p][0];
            {
                const unsigned long long g1 = wpart[p][1];
                const unsigned long long g2 = wpart[p][2];
                const unsigned long long g3 = wpart[p][3];
                g = (g1 < g) ? g1 : g;
                g = (g2 < g) ? g2 : g;
                g = (g3 < g) ? g3 : g;
            }
            if (g == EXCL) break;
            const int jwin = (int)(g & 2047u);
            if (t == 0) reinterpret_cast<unsigned char*>(selq)[jwin] = 1;
            if (lmin == g) {
                unsigned long long nm = EXCL;
                #pragma unroll
                for (int k = 0; k < EPT; ++k) {
                    if (key[k] == g) key[k] = EXCL;
                    nm = (key[k] < nm) ? key[k] : nm;
                }
                lmin = nm;
            }
        }
    }
    __syncthreads();  // sel-bytemap visible to all

    // Output: depot_i==0 here, so mask = depot_j | (j==i) | selected(j).
    const unsigned long long selbits = selq[t];
    const int4 p0 = reinterpret_cast<const int4*>(deprow + j0)[0];
    const int4 p1 = reinterpret_cast<const int4*>(deprow + j0)[1];
    const int dpv[EPT] = {p0.x, p0.y, p0.z, p0.w, p1.x, p1.y, p1.z, p1.w};

    float ov[EPT];
    #pragma unroll
    for (int k = 0; k < EPT; ++k) {
        const int j = j0 + k;
        const bool sel = ((selbits >> (8 * k)) & 0xffull) != 0ull;
        const bool one = (dpv[k] != 0) | (j == i) | sel;
        ov[k] = one ? 1.0f : 0.0f;
    }
    float4* o4 = reinterpret_cast<float4*>(orow + j0);
    o4[0] = make_float4(ov[0], ov[1], ov[2], ov[3]);
    o4[1] = make_float4(ov[4], ov[5], ov[6], ov[7]);
}

extern "C" void kernel_launch(void* const* d_in, const int* in_sizes, int n_in,
                              void* d_out, int out_size, void* d_ws, size_t ws_size,
                              hipStream_t stream) {
    const float* D     = (const float*)d_in[0];   // distance_matrix [B,N,N]
    // d_in[1] = max_dist — provably irrelevant (blocked entries never survive)
    const int*   TWC   = (const int*)d_in[2];     // time_window_compatibility [B,N,N]
    const int*   depot = (const int*)d_in[3];     // depot [B,N]
    // d_in[4] = num_neighbors_encoder == 16 (compile-time KNB)

    float* outp = (float*)d_out;
    const int rows = in_sizes[3];                 // B*N = 16384

    encoder_mask_kernel<<<rows, TPB, 0, stream>>>(D, TWC, depot, outp);
}